// Round 12
// baseline (562.636 us; speedup 1.0000x reference)
//
#include <hip/hip_runtime.h>
#include <hip/hip_bf16.h>
#include <hip/hip_fp16.h>
#include <math.h>

// ---------------------------------------------------------------------------
// GAT (3 layers, heads=4/4/1, hid=32) + final linear.
// R23: revert R22's layer-2-into-gather fusion (it halved the gather
//      kernel's MLP: VGPR 32->40, occ 72->59%, same FETCH at half the fill
//      BW -> 147us). Back to R21 structure, keeping only low-risk cuts:
//      - zero1 kernel -> hipMemsetAsync
//      - 3 wpack launches -> 1
//      - rank array eliminated: scatter uses atomic cursor (cursor written
//        by scan_add). Saves 13.6 MB of rank traffic.
//      Fused gather kernels are REGISTER-LEAN ON PURPOSE - do not add state.
// ---------------------------------------------------------------------------

#define NEG_SLOPE 0.2f

typedef __attribute__((ext_vector_type(8))) _Float16 f16x8;
typedef __attribute__((ext_vector_type(4))) float    f32x4;

struct h4pack { __half2 a, b; };   // 4 halves = 8 B

// ---------------- CSR build ----------------

__global__ void count_kernel(const int* __restrict__ ei, int eraw, int n,
                             int* __restrict__ deg) {
    int i = blockIdx.x * blockDim.x + threadIdx.x;
    int etot = eraw + n;
    if (i >= etot) return;
    int dst = (i < eraw) ? ei[eraw + i] : (i - eraw);
    atomicAdd(&deg[dst], 1);
}

__global__ __launch_bounds__(1024)
void scan_local_kernel(const int* __restrict__ deg, int* __restrict__ rowptr,
                       int* __restrict__ bsum, int n) {
    __shared__ int buf[1024];
    int tid = threadIdx.x;
    int i = blockIdx.x * 1024 + tid;
    int v = (i < n) ? deg[i] : 0;
    buf[tid] = v;
    __syncthreads();
    for (int off = 1; off < 1024; off <<= 1) {
        int t = (tid >= off) ? buf[tid - off] : 0;
        __syncthreads();
        buf[tid] += t;
        __syncthreads();
    }
    if (i < n) rowptr[i] = buf[tid] - v;
    if (tid == 1023) bsum[blockIdx.x] = buf[1023];
}

__global__ __launch_bounds__(128)
void scan_sums_kernel(const int* __restrict__ bsum, int* __restrict__ boffs, int nb) {
    __shared__ int buf[128];
    int tid = threadIdx.x;
    int v = (tid < nb) ? bsum[tid] : 0;
    buf[tid] = v;
    __syncthreads();
    for (int off = 1; off < 128; off <<= 1) {
        int t = (tid >= off) ? buf[tid - off] : 0;
        __syncthreads();
        buf[tid] += t;
        __syncthreads();
    }
    if (tid < nb) boffs[tid] = buf[tid] - v;
}

__global__ void scan_add_kernel(int* __restrict__ rowptr, int* __restrict__ cursor,
                                const int* __restrict__ boffs, int n, int etot) {
    int i = blockIdx.x * blockDim.x + threadIdx.x;
    if (i < n) {
        int v = rowptr[i] + boffs[i >> 10];
        rowptr[i] = v;
        cursor[i] = v;
    }
    if (i == 0) rowptr[n] = etot;
}

__global__ void scatter_kernel(const int* __restrict__ ei, int eraw, int n,
                               int* __restrict__ cursor, int* __restrict__ csr_src) {
    int i = blockIdx.x * blockDim.x + threadIdx.x;
    int etot = eraw + n;
    if (i >= etot) return;
    int src, dst;
    if (i < eraw) { src = ei[i]; dst = ei[eraw + i]; }
    else          { src = i - eraw; dst = src; }
    int pos = atomicAdd(&cursor[dst], 1);
    csr_src[pos] = src;
}

// ---------------- combined weight prep -------------------------------------
// Wp0/Wp1: 128x128 -> MFMA fragment order (16384 each).
// Wp2: 128x32 -> fragment order (4096).

__global__ void wpack_all_kernel(const float* __restrict__ W0, const float* __restrict__ W1,
                                 const float* __restrict__ W2,
                                 __half* __restrict__ Wp0, __half* __restrict__ Wp1,
                                 __half* __restrict__ Wp2) {
    int i = blockIdx.x * blockDim.x + threadIdx.x;   // 0..36863
    if (i < 32768) {
        const float* W = (i < 16384) ? W0 : W1;
        __half* Wp     = (i < 16384) ? Wp0 : Wp1;
        int ii   = i & 16383;
        int j    = ii & 7;
        int lane = (ii >> 3) & 63;
        int ks   = (ii >> 9) & 3;
        int ct   = ii >> 11;
        int k = ks * 32 + (lane >> 4) * 8 + j;
        int c = ct * 16 + (lane & 15);
        Wp[ii] = __float2half(W[k * 128 + c]);
    } else if (i < 36864) {
        int ii   = i - 32768;             // 0..4095
        int j    = ii & 7;
        int lane = (ii >> 3) & 63;
        int ks   = (ii >> 9) & 3;
        int ct   = ii >> 11;              // 0..1
        int k = ks * 32 + (lane >> 4) * 8 + j;
        int c = ct * 16 + (lane & 15);
        Wp2[ii] = __float2half(W2[k * 32 + c]);
    }
}

// ---------------- swapped-operand MFMA GEMM + fused attn-coef (L0/L1) ------

template <bool F32IN>
__global__ __launch_bounds__(256)
void gemm_mfma_coef_kernel(const void* __restrict__ Xv, const __half* __restrict__ Wp,
                           const float* __restrict__ a_s, const float* __restrict__ a_d,
                           __half* __restrict__ H, float* __restrict__ as_out,
                           float* __restrict__ ad_out, int n) {
    int t = threadIdx.x;
    int lane = t & 63;
    int wave = t >> 6;
    int l15 = lane & 15;
    int kg  = lane >> 4;                 // 0..3
    int wbase = blockIdx.x * 128 + wave * 32;

    int node0 = wbase + l15;
    int node1 = wbase + 16 + l15;
    int n0c = (node0 < n) ? node0 : 0;
    int n1c = (node1 < n) ? node1 : 0;

    f32x4 acc[2][8];
#pragma unroll
    for (int tt = 0; tt < 2; tt++)
#pragma unroll
        for (int i = 0; i < 8; i++) acc[tt][i] = (f32x4){0.f, 0.f, 0.f, 0.f};

#pragma unroll
    for (int ks = 0; ks < 4; ks++) {
        f16x8 b0, b1;                    // X fragments (B operand: X^T)
        if constexpr (F32IN) {
            const float* X = (const float*)Xv;
            const float* p0 = X + (size_t)n0c * 128 + kg * 8 + ks * 32;
            const float* p1 = X + (size_t)n1c * 128 + kg * 8 + ks * 32;
            float4 x0 = *(const float4*)(p0), x1 = *(const float4*)(p0 + 4);
            b0[0] = (_Float16)x0.x; b0[1] = (_Float16)x0.y; b0[2] = (_Float16)x0.z; b0[3] = (_Float16)x0.w;
            b0[4] = (_Float16)x1.x; b0[5] = (_Float16)x1.y; b0[6] = (_Float16)x1.z; b0[7] = (_Float16)x1.w;
            float4 y0 = *(const float4*)(p1), y1 = *(const float4*)(p1 + 4);
            b1[0] = (_Float16)y0.x; b1[1] = (_Float16)y0.y; b1[2] = (_Float16)y0.z; b1[3] = (_Float16)y0.w;
            b1[4] = (_Float16)y1.x; b1[5] = (_Float16)y1.y; b1[6] = (_Float16)y1.z; b1[7] = (_Float16)y1.w;
        } else {
            const __half* X = (const __half*)Xv;
            b0 = *(const f16x8*)(X + (size_t)n0c * 128 + kg * 8 + ks * 32);
            b1 = *(const f16x8*)(X + (size_t)n1c * 128 + kg * 8 + ks * 32);
        }
#pragma unroll
        for (int ct = 0; ct < 8; ct++) {
            f16x8 a = *(const f16x8*)(Wp + (size_t)((ct * 4 + ks) * 64 + lane) * 8);
            acc[0][ct] = __builtin_amdgcn_mfma_f32_16x16x32_f16(a, b0, acc[0][ct], 0, 0, 0);
            acc[1][ct] = __builtin_amdgcn_mfma_f32_16x16x32_f16(a, b1, acc[1][ct], 0, 0, 0);
        }
    }

    // packed 8-B H store straight from registers
#pragma unroll
    for (int tt = 0; tt < 2; tt++) {
        int node = wbase + tt * 16 + l15;
        if (node < n) {
#pragma unroll
            for (int ct = 0; ct < 8; ct++) {
                h4pack p;
                p.a = __floats2half2_rn(acc[tt][ct][0], acc[tt][ct][1]);
                p.b = __floats2half2_rn(acc[tt][ct][2], acc[tt][ct][3]);
                *(h4pack*)(H + (size_t)node * 128 + ct * 16 + kg * 4) = p;
            }
        }
    }

    // fused attn-coef
#pragma unroll
    for (int tt = 0; tt < 2; tt++) {
        int node = wbase + tt * 16 + l15;
#pragma unroll
        for (int h = 0; h < 4; h++) {
            float s = 0.f, d = 0.f;
#pragma unroll
            for (int q = 0; q < 2; q++) {
                int ct = 2 * h + q;
#pragma unroll
                for (int r = 0; r < 4; r++) {
                    int c = q * 16 + kg * 4 + r;       // channel within head
                    float v = acc[tt][ct][r];
                    s += v * a_s[h * 32 + c];
                    d += v * a_d[h * 32 + c];
                }
            }
            s += __shfl_xor(s, 16); s += __shfl_xor(s, 32);
            d += __shfl_xor(d, 16); d += __shfl_xor(d, 32);
            if (kg == 0 && node < n) {
                as_out[(size_t)node * 4 + h] = s;
                ad_out[(size_t)node * 4 + h] = d;
            }
        }
    }
}

// ---------------- layer-2 MFMA GEMM + fused coef ---------------------------

__global__ __launch_bounds__(256)
void gemm_mfma_l2_kernel(const __half* __restrict__ X, const __half* __restrict__ Wp,
                         const float* __restrict__ a_s, const float* __restrict__ a_d,
                         __half* __restrict__ H, float* __restrict__ as_out,
                         float* __restrict__ ad_out, int n) {
    __shared__ __half hs[4][32][40];    // 10,240 B; 80 B/row: 16B-aligned
    int t = threadIdx.x;
    int wave = t >> 6, lane = t & 63;
    int l15 = lane & 15;
    int kg  = lane >> 4;
    int wbase = blockIdx.x * 128 + wave * 32;

    int row0 = wbase + l15;
    int row1 = wbase + 16 + l15;
    int r0c = (row0 < n) ? row0 : 0;
    int r1c = (row1 < n) ? row1 : 0;

    f32x4 acc[2][2];
#pragma unroll
    for (int tt = 0; tt < 2; tt++)
#pragma unroll
        for (int i = 0; i < 2; i++) acc[tt][i] = (f32x4){0.f, 0.f, 0.f, 0.f};

#pragma unroll
    for (int ks = 0; ks < 4; ks++) {
        f16x8 a0 = *(const f16x8*)(X + (size_t)r0c * 128 + kg * 8 + ks * 32);
        f16x8 a1 = *(const f16x8*)(X + (size_t)r1c * 128 + kg * 8 + ks * 32);
#pragma unroll
        for (int ct = 0; ct < 2; ct++) {
            f16x8 b = *(const f16x8*)(Wp + (size_t)((ct * 4 + ks) * 64 + lane) * 8);
            acc[0][ct] = __builtin_amdgcn_mfma_f32_16x16x32_f16(a0, b, acc[0][ct], 0, 0, 0);
            acc[1][ct] = __builtin_amdgcn_mfma_f32_16x16x32_f16(a1, b, acc[1][ct], 0, 0, 0);
        }
    }

#pragma unroll
    for (int tt = 0; tt < 2; tt++)
#pragma unroll
        for (int ct = 0; ct < 2; ct++)
#pragma unroll
            for (int r = 0; r < 4; r++)
                hs[wave][tt * 16 + kg * 4 + r][ct * 16 + l15] = __float2half(acc[tt][ct][r]);
    __syncthreads();

    // coalesced H store: 2 iters x (16 rows x 64 B contiguous), 16 B/lane
#pragma unroll
    for (int it = 0; it < 2; it++) {
        int lr    = it * 16 + (lane >> 2);     // 0..31
        int chunk = lane & 3;                  // 16B chunk within 64B row
        int orow  = wbase + lr;
        if (orow < n) {
            uint4 v = *(const uint4*)&hs[wave][lr][chunk * 8];
            *(uint4*)(H + (size_t)orow * 32 + chunk * 8) = v;
        }
    }

    // coef (1 head): lanes 0..31, row = lane
    if (lane < 32) {
        int orow = wbase + lane;
        if (orow < n) {
            const __half2* hp = (const __half2*)&hs[wave][lane][0];
            float s = 0.f, d = 0.f;
#pragma unroll
            for (int c2 = 0; c2 < 16; c2++) {
                float2 v = __half22float2(hp[c2]);
                s += v.x * a_s[2 * c2] + v.y * a_s[2 * c2 + 1];
                d += v.x * a_d[2 * c2] + v.y * a_d[2 * c2 + 1];
            }
            as_out[orow] = s;
            ad_out[orow] = d;
        }
    }
}

// ---------------- fused online-softmax aggregation, fp16 gathers -----------

__global__ __launch_bounds__(256)
void gat_fused_f16_kernel(const __half* __restrict__ Hm,
                          const float* __restrict__ as_,
                          const float* __restrict__ ad_,
                          const int* __restrict__ rowptr,
                          const int* __restrict__ csr,
                          const float* __restrict__ bias,
                          __half* __restrict__ out, int n) {
    constexpr int GS = 32;
    int t = threadIdx.x;
    int node = blockIdx.x * 8 + (t >> 5);
    if (node >= n) return;
    int tl = t & 31;
    int h  = tl >> 3;
    int k8 = tl & 7;
    const uint2* H8 = (const uint2*)Hm;     // 8 B = 4 halves per lane
    int e0 = rowptr[node], e1 = rowptr[node + 1];
    float ad_d = ad_[(size_t)node * 4 + h];

    int  ce  = e0 + k8;
    bool vA  = ce < e1;
    int  idxA = vA ? csr[ce] : 0;
    float asA = vA ? as_[(size_t)idxA * 4 + h] : 0.f;

    float m = -INFINITY, l = 0.f;
    float4 acc = make_float4(0.f, 0.f, 0.f, 0.f);

    for (int eb = e0; eb < e1; eb += 8) {
        uint2 u[8];
#pragma unroll
        for (int j = 0; j < 8; j++) {
            int src = __shfl(idxA, j, 8);
            u[j] = H8[(size_t)src * GS + tl];
        }

        int  ne  = eb + 8 + k8;
        bool vB  = ne < e1;
        int  idxB = vB ? csr[ne] : 0;
        float asB = vB ? as_[(size_t)idxB * 4 + h] : 0.f;

        float el = asA + ad_d;
        el = (el > 0.f) ? el : NEG_SLOPE * el;
        el = vA ? el : -INFINITY;

        float cm = el;
        cm = fmaxf(cm, __shfl_xor(cm, 1, 8));
        cm = fmaxf(cm, __shfl_xor(cm, 2, 8));
        cm = fmaxf(cm, __shfl_xor(cm, 4, 8));
        float m_new = fmaxf(m, cm);
        float scale = __expf(m - m_new);
        float p = vA ? __expf(el - m_new) : 0.f;

        float ps = p;
        ps += __shfl_xor(ps, 1, 8);
        ps += __shfl_xor(ps, 2, 8);
        ps += __shfl_xor(ps, 4, 8);
        l = l * scale + ps;
        acc.x *= scale; acc.y *= scale; acc.z *= scale; acc.w *= scale;
        m = m_new;

#pragma unroll
        for (int j = 0; j < 8; j++) {
            float pj  = __shfl(p, j, 8);
            float2 f01 = __half22float2(*(const __half2*)&u[j].x);
            float2 f23 = __half22float2(*(const __half2*)&u[j].y);
            acc.x += pj * f01.x; acc.y += pj * f01.y;
            acc.z += pj * f23.x; acc.w += pj * f23.y;
        }
        idxA = idxB; asA = asB; vA = vB;
    }

    float li = 1.f / (l + 1e-16f);
    float4 b4 = ((const float4*)bias)[tl];
    float4 o;
    o.x = fmaxf(acc.x * li + b4.x, 0.f);
    o.y = fmaxf(acc.y * li + b4.y, 0.f);
    o.z = fmaxf(acc.z * li + b4.z, 0.f);
    o.w = fmaxf(acc.w * li + b4.w, 0.f);
    h4pack po;
    po.a = __floats2half2_rn(o.x, o.y);
    po.b = __floats2half2_rn(o.z, o.w);
    ((h4pack*)out)[(size_t)node * 32 + tl] = po;
}

// ---------------- layer-2 fused: fp16 gathers + bias/relu + final linear ---

__global__ __launch_bounds__(256)
void gat_fused_l2_kernel(const __half* __restrict__ Hm,
                         const float* __restrict__ as_,
                         const float* __restrict__ ad_,
                         const int* __restrict__ rowptr,
                         const int* __restrict__ csr,
                         const float* __restrict__ bias,
                         const float* __restrict__ lw,
                         const float* __restrict__ lb,
                         float* __restrict__ out, int n) {
    int t = threadIdx.x;
    int node = blockIdx.x * 32 + (t >> 3);
    if (node >= n) return;
    int tl = t & 7;
    const uint2* H8 = (const uint2*)Hm;     // row = 8 uint2 (32 halves)
    int e0 = rowptr[node], e1 = rowptr[node + 1];
    float ad_d = ad_[node];

    int  ce  = e0 + tl;
    bool vA  = ce < e1;
    int  idxA = vA ? csr[ce] : 0;
    float asA = vA ? as_[idxA] : 0.f;

    float m = -INFINITY, l = 0.f;
    float4 acc = make_float4(0.f, 0.f, 0.f, 0.f);

    for (int eb = e0; eb < e1; eb += 8) {
        uint2 u[8];
#pragma unroll
        for (int j = 0; j < 8; j++) {
            int src = __shfl(idxA, j, 8);
            u[j] = H8[(size_t)src * 8 + tl];
        }

        int  ne  = eb + 8 + tl;
        bool vB  = ne < e1;
        int  idxB = vB ? csr[ne] : 0;
        float asB = vB ? as_[idxB] : 0.f;

        float el = asA + ad_d;
        el = (el > 0.f) ? el : NEG_SLOPE * el;
        el = vA ? el : -INFINITY;

        float cm = el;
        cm = fmaxf(cm, __shfl_xor(cm, 1, 8));
        cm = fmaxf(cm, __shfl_xor(cm, 2, 8));
        cm = fmaxf(cm, __shfl_xor(cm, 4, 8));
        float m_new = fmaxf(m, cm);
        float scale = __expf(m - m_new);
        float p = vA ? __expf(el - m_new) : 0.f;

        float ps = p;
        ps += __shfl_xor(ps, 1, 8);
        ps += __shfl_xor(ps, 2, 8);
        ps += __shfl_xor(ps, 4, 8);
        l = l * scale + ps;
        acc.x *= scale; acc.y *= scale; acc.z *= scale; acc.w *= scale;
        m = m_new;

#pragma unroll
        for (int j = 0; j < 8; j++) {
            float pj  = __shfl(p, j, 8);
            float2 f01 = __half22float2(*(const __half2*)&u[j].x);
            float2 f23 = __half22float2(*(const __half2*)&u[j].y);
            acc.x += pj * f01.x; acc.y += pj * f01.y;
            acc.z += pj * f23.x; acc.w += pj * f23.y;
        }
        idxA = idxB; asA = asB; vA = vB;
    }

    float li = 1.f / (l + 1e-16f);
    float4 b4 = ((const float4*)bias)[tl];
    float4 o;
    o.x = fmaxf(acc.x * li + b4.x, 0.f);
    o.y = fmaxf(acc.y * li + b4.y, 0.f);
    o.z = fmaxf(acc.z * li + b4.z, 0.f);
    o.w = fmaxf(acc.w * li + b4.w, 0.f);

    // fused final linear: lane tl computes classes tl + 8c (c = 0..4)
    float fin0 = lb[tl];
    float fin1 = lb[tl + 8];
    float fin2 = lb[tl + 16];
    float fin3 = lb[tl + 24];
    float fin4 = lb[tl + 32];
#pragma unroll
    for (int j = 0; j < 8; j++) {
        float vx = __shfl(o.x, j, 8);
        float vy = __shfl(o.y, j, 8);
        float vz = __shfl(o.z, j, 8);
        float vw = __shfl(o.w, j, 8);
        const float* l0 = lw + (size_t)(4 * j) * 40;   // rows 4j..4j+3 of lw[32,40]
#pragma unroll
        for (int c = 0; c < 5; c++) {
            int cls = tl + 8 * c;
            float v = vx * l0[cls] + vy * l0[40 + cls] + vz * l0[80 + cls] + vw * l0[120 + cls];
            if (c == 0) fin0 += v;
            else if (c == 1) fin1 += v;
            else if (c == 2) fin2 += v;
            else if (c == 3) fin3 += v;
            else fin4 += v;
        }
    }
    float* op = out + (size_t)node * 40;
    op[tl]      = fin0;
    op[tl + 8]  = fin1;
    op[tl + 16] = fin2;
    op[tl + 24] = fin3;
    op[tl + 32] = fin4;
}

// ---------------- launch ----------------

extern "C" void kernel_launch(void* const* d_in, const int* in_sizes, int n_in,
                              void* d_out, int out_size, void* d_ws, size_t ws_size,
                              hipStream_t stream) {
    const float* x   = (const float*)d_in[0];
    const int*   ei  = (const int*)d_in[1];
    const float* W0  = (const float*)d_in[2];
    const float* as0 = (const float*)d_in[3];
    const float* ad0 = (const float*)d_in[4];
    const float* b0  = (const float*)d_in[5];
    const float* W1  = (const float*)d_in[6];
    const float* as1 = (const float*)d_in[7];
    const float* ad1 = (const float*)d_in[8];
    const float* b1  = (const float*)d_in[9];
    const float* W2  = (const float*)d_in[10];
    const float* as2 = (const float*)d_in[11];
    const float* ad2 = (const float*)d_in[12];
    const float* b2  = (const float*)d_in[13];
    const float* lw  = (const float*)d_in[14];
    const float* lb  = (const float*)d_in[15];
    float* out = (float*)d_out;

    const int n    = in_sizes[0] / 128;   // 100000 (= 32 * 3125)
    const int eraw = in_sizes[1] / 2;     // 1600000
    const int etot = eraw + n;
    const int nb   = (n + 1023) / 1024;

    char* wsp = (char*)d_ws;
    size_t off = 0;
    auto alloc = [&](size_t bytes) -> void* {
        void* p = wsp + off;
        off += (bytes + 255) & ~(size_t)255;
        return p;
    };
    __half* h16    = (__half*)alloc((size_t)n * 128 * 2);  // per-layer h table
    __half* buf16  = (__half*)alloc((size_t)n * 128 * 2);  // inter-layer activations
    __half* h2     = (__half*)alloc((size_t)n * 32 * 2);   // layer-2 h table
    __half* Wp0    = (__half*)alloc((size_t)128 * 128 * 2);
    __half* Wp1    = (__half*)alloc((size_t)128 * 128 * 2);
    __half* Wp2    = (__half*)alloc((size_t)128 * 32 * 2);
    float*  asb    = (float*)alloc((size_t)n * 4 * 4);
    float*  adb    = (float*)alloc((size_t)n * 4 * 4);
    float*  asb2   = (float*)alloc((size_t)n * 4);
    float*  adb2   = (float*)alloc((size_t)n * 4);
    int*    deg    = (int*)alloc((size_t)n * 4);
    int*    cursor = (int*)alloc((size_t)n * 4);
    int*    rowptr = (int*)alloc((size_t)(n + 1) * 4);
    int*    csr    = (int*)alloc((size_t)etot * 4);
    int*    bsum   = (int*)alloc((size_t)nb * 4);
    int*    boffs  = (int*)alloc((size_t)nb * 4);

    // --- CSR build + weight prep ---
    hipMemsetAsync(deg, 0, (size_t)n * 4, stream);
    count_kernel<<<(etot + 255) / 256, 256, 0, stream>>>(ei, eraw, n, deg);
    wpack_all_kernel<<<144, 256, 0, stream>>>(W0, W1, W2, Wp0, Wp1, Wp2);
    scan_local_kernel<<<nb, 1024, 0, stream>>>(deg, rowptr, bsum, n);
    scan_sums_kernel<<<1, 128, 0, stream>>>(bsum, boffs, nb);
    scan_add_kernel<<<(n + 255) / 256, 256, 0, stream>>>(rowptr, cursor, boffs, n, etot);
    scatter_kernel<<<(etot + 255) / 256, 256, 0, stream>>>(ei, eraw, n, cursor, csr);

    const int gblocks = (n + 127) / 128;

    // --- layer 0: 128 -> 4x32, concat ---
    gemm_mfma_coef_kernel<true><<<gblocks, 256, 0, stream>>>(x, Wp0, as0, ad0, h16, asb, adb, n);
    gat_fused_f16_kernel<<<(n + 7) / 8, 256, 0, stream>>>(h16, asb, adb, rowptr, csr, b0, buf16, n);

    // --- layer 1: 128 -> 4x32, concat ---
    gemm_mfma_coef_kernel<false><<<gblocks, 256, 0, stream>>>(buf16, Wp1, as1, ad1, h16, asb, adb, n);
    gat_fused_f16_kernel<<<(n + 7) / 8, 256, 0, stream>>>(h16, asb, adb, rowptr, csr, b1, buf16, n);

    // --- layer 2: 128 -> 1x32 (MFMA + fused coef), + fused final linear ---
    gemm_mfma_l2_kernel<<<gblocks, 256, 0, stream>>>(buf16, Wp2, as2, ad2, h2, asb2, adb2, n);
    gat_fused_l2_kernel<<<(n + 31) / 32, 256, 0, stream>>>(h2, asb2, adb2, rowptr, csr, b2, lw, lb, out, n);
}

// Round 13
// 457.825 us; speedup vs baseline: 1.2289x; 1.2289x over previous
//
#include <hip/hip_runtime.h>
#include <hip/hip_bf16.h>
#include <hip/hip_fp16.h>
#include <math.h>

// ---------------------------------------------------------------------------
// GAT (3 layers, heads=4/4/1, hid=32) + final linear.
// R24: revert R23's atomic-cursor scatter (137.9us: atomicAdd -> dependent
//      random store serializes on device-atomic latency, WRITE 108 MB).
//      Back to R21's two-phase CSR (count_rank stores rank; scatter2's
//      address comes from cached reads -> latency-decoupled store stream).
//      Kept from R23: deg zero via hipMemsetAsync, single wpack launch.
//      DO NOT: add state to gat_fused kernels (R22), put stores behind
//      atomics (R23). Those two regressions are documented dead ends.
// ---------------------------------------------------------------------------

#define NEG_SLOPE 0.2f

typedef __attribute__((ext_vector_type(8))) _Float16 f16x8;
typedef __attribute__((ext_vector_type(4))) float    f32x4;

struct h4pack { __half2 a, b; };   // 4 halves = 8 B

// ---------------- CSR build ----------------

__global__ void count_rank_kernel(const int* __restrict__ ei, int eraw, int n,
                                  int* __restrict__ deg, int* __restrict__ rank) {
    int i = blockIdx.x * blockDim.x + threadIdx.x;
    int etot = eraw + n;
    if (i >= etot) return;
    int dst = (i < eraw) ? ei[eraw + i] : (i - eraw);
    rank[i] = atomicAdd(&deg[dst], 1);
}

__global__ __launch_bounds__(1024)
void scan_local_kernel(const int* __restrict__ deg, int* __restrict__ rowptr,
                       int* __restrict__ bsum, int n) {
    __shared__ int buf[1024];
    int tid = threadIdx.x;
    int i = blockIdx.x * 1024 + tid;
    int v = (i < n) ? deg[i] : 0;
    buf[tid] = v;
    __syncthreads();
    for (int off = 1; off < 1024; off <<= 1) {
        int t = (tid >= off) ? buf[tid - off] : 0;
        __syncthreads();
        buf[tid] += t;
        __syncthreads();
    }
    if (i < n) rowptr[i] = buf[tid] - v;
    if (tid == 1023) bsum[blockIdx.x] = buf[1023];
}

__global__ __launch_bounds__(128)
void scan_sums_kernel(const int* __restrict__ bsum, int* __restrict__ boffs, int nb) {
    __shared__ int buf[128];
    int tid = threadIdx.x;
    int v = (tid < nb) ? bsum[tid] : 0;
    buf[tid] = v;
    __syncthreads();
    for (int off = 1; off < 128; off <<= 1) {
        int t = (tid >= off) ? buf[tid - off] : 0;
        __syncthreads();
        buf[tid] += t;
        __syncthreads();
    }
    if (tid < nb) boffs[tid] = buf[tid] - v;
}

__global__ void scan_add_kernel(int* __restrict__ rowptr, const int* __restrict__ boffs,
                                int n, int etot) {
    int i = blockIdx.x * blockDim.x + threadIdx.x;
    if (i < n) rowptr[i] += boffs[i >> 10];
    if (i == 0) rowptr[n] = etot;
}

__global__ void scatter2_kernel(const int* __restrict__ ei, const int* __restrict__ rank,
                                int eraw, int n, const int* __restrict__ rowptr,
                                int* __restrict__ csr_src) {
    int i = blockIdx.x * blockDim.x + threadIdx.x;
    int etot = eraw + n;
    if (i >= etot) return;
    int src, dst;
    if (i < eraw) { src = ei[i]; dst = ei[eraw + i]; }
    else          { src = i - eraw; dst = src; }
    csr_src[rowptr[dst] + rank[i]] = src;
}

// ---------------- combined weight prep -------------------------------------
// Wp0/Wp1: 128x128 -> MFMA fragment order (16384 each).
// Wp2: 128x32 -> fragment order (4096).

__global__ void wpack_all_kernel(const float* __restrict__ W0, const float* __restrict__ W1,
                                 const float* __restrict__ W2,
                                 __half* __restrict__ Wp0, __half* __restrict__ Wp1,
                                 __half* __restrict__ Wp2) {
    int i = blockIdx.x * blockDim.x + threadIdx.x;   // 0..36863
    if (i < 32768) {
        const float* W = (i < 16384) ? W0 : W1;
        __half* Wp     = (i < 16384) ? Wp0 : Wp1;
        int ii   = i & 16383;
        int j    = ii & 7;
        int lane = (ii >> 3) & 63;
        int ks   = (ii >> 9) & 3;
        int ct   = ii >> 11;
        int k = ks * 32 + (lane >> 4) * 8 + j;
        int c = ct * 16 + (lane & 15);
        Wp[ii] = __float2half(W[k * 128 + c]);
    } else if (i < 36864) {
        int ii   = i - 32768;             // 0..4095
        int j    = ii & 7;
        int lane = (ii >> 3) & 63;
        int ks   = (ii >> 9) & 3;
        int ct   = ii >> 11;              // 0..1
        int k = ks * 32 + (lane >> 4) * 8 + j;
        int c = ct * 16 + (lane & 15);
        Wp2[ii] = __float2half(W2[k * 32 + c]);
    }
}

// ---------------- swapped-operand MFMA GEMM + fused attn-coef (L0/L1) ------

template <bool F32IN>
__global__ __launch_bounds__(256)
void gemm_mfma_coef_kernel(const void* __restrict__ Xv, const __half* __restrict__ Wp,
                           const float* __restrict__ a_s, const float* __restrict__ a_d,
                           __half* __restrict__ H, float* __restrict__ as_out,
                           float* __restrict__ ad_out, int n) {
    int t = threadIdx.x;
    int lane = t & 63;
    int wave = t >> 6;
    int l15 = lane & 15;
    int kg  = lane >> 4;                 // 0..3
    int wbase = blockIdx.x * 128 + wave * 32;

    int node0 = wbase + l15;
    int node1 = wbase + 16 + l15;
    int n0c = (node0 < n) ? node0 : 0;
    int n1c = (node1 < n) ? node1 : 0;

    f32x4 acc[2][8];
#pragma unroll
    for (int tt = 0; tt < 2; tt++)
#pragma unroll
        for (int i = 0; i < 8; i++) acc[tt][i] = (f32x4){0.f, 0.f, 0.f, 0.f};

#pragma unroll
    for (int ks = 0; ks < 4; ks++) {
        f16x8 b0, b1;                    // X fragments (B operand: X^T)
        if constexpr (F32IN) {
            const float* X = (const float*)Xv;
            const float* p0 = X + (size_t)n0c * 128 + kg * 8 + ks * 32;
            const float* p1 = X + (size_t)n1c * 128 + kg * 8 + ks * 32;
            float4 x0 = *(const float4*)(p0), x1 = *(const float4*)(p0 + 4);
            b0[0] = (_Float16)x0.x; b0[1] = (_Float16)x0.y; b0[2] = (_Float16)x0.z; b0[3] = (_Float16)x0.w;
            b0[4] = (_Float16)x1.x; b0[5] = (_Float16)x1.y; b0[6] = (_Float16)x1.z; b0[7] = (_Float16)x1.w;
            float4 y0 = *(const float4*)(p1), y1 = *(const float4*)(p1 + 4);
            b1[0] = (_Float16)y0.x; b1[1] = (_Float16)y0.y; b1[2] = (_Float16)y0.z; b1[3] = (_Float16)y0.w;
            b1[4] = (_Float16)y1.x; b1[5] = (_Float16)y1.y; b1[6] = (_Float16)y1.z; b1[7] = (_Float16)y1.w;
        } else {
            const __half* X = (const __half*)Xv;
            b0 = *(const f16x8*)(X + (size_t)n0c * 128 + kg * 8 + ks * 32);
            b1 = *(const f16x8*)(X + (size_t)n1c * 128 + kg * 8 + ks * 32);
        }
#pragma unroll
        for (int ct = 0; ct < 8; ct++) {
            f16x8 a = *(const f16x8*)(Wp + (size_t)((ct * 4 + ks) * 64 + lane) * 8);
            acc[0][ct] = __builtin_amdgcn_mfma_f32_16x16x32_f16(a, b0, acc[0][ct], 0, 0, 0);
            acc[1][ct] = __builtin_amdgcn_mfma_f32_16x16x32_f16(a, b1, acc[1][ct], 0, 0, 0);
        }
    }

    // packed 8-B H store straight from registers
#pragma unroll
    for (int tt = 0; tt < 2; tt++) {
        int node = wbase + tt * 16 + l15;
        if (node < n) {
#pragma unroll
            for (int ct = 0; ct < 8; ct++) {
                h4pack p;
                p.a = __floats2half2_rn(acc[tt][ct][0], acc[tt][ct][1]);
                p.b = __floats2half2_rn(acc[tt][ct][2], acc[tt][ct][3]);
                *(h4pack*)(H + (size_t)node * 128 + ct * 16 + kg * 4) = p;
            }
        }
    }

    // fused attn-coef
#pragma unroll
    for (int tt = 0; tt < 2; tt++) {
        int node = wbase + tt * 16 + l15;
#pragma unroll
        for (int h = 0; h < 4; h++) {
            float s = 0.f, d = 0.f;
#pragma unroll
            for (int q = 0; q < 2; q++) {
                int ct = 2 * h + q;
#pragma unroll
                for (int r = 0; r < 4; r++) {
                    int c = q * 16 + kg * 4 + r;       // channel within head
                    float v = acc[tt][ct][r];
                    s += v * a_s[h * 32 + c];
                    d += v * a_d[h * 32 + c];
                }
            }
            s += __shfl_xor(s, 16); s += __shfl_xor(s, 32);
            d += __shfl_xor(d, 16); d += __shfl_xor(d, 32);
            if (kg == 0 && node < n) {
                as_out[(size_t)node * 4 + h] = s;
                ad_out[(size_t)node * 4 + h] = d;
            }
        }
    }
}

// ---------------- layer-2 MFMA GEMM + fused coef ---------------------------

__global__ __launch_bounds__(256)
void gemm_mfma_l2_kernel(const __half* __restrict__ X, const __half* __restrict__ Wp,
                         const float* __restrict__ a_s, const float* __restrict__ a_d,
                         __half* __restrict__ H, float* __restrict__ as_out,
                         float* __restrict__ ad_out, int n) {
    __shared__ __half hs[4][32][40];    // 10,240 B; 80 B/row: 16B-aligned
    int t = threadIdx.x;
    int wave = t >> 6, lane = t & 63;
    int l15 = lane & 15;
    int kg  = lane >> 4;
    int wbase = blockIdx.x * 128 + wave * 32;

    int row0 = wbase + l15;
    int row1 = wbase + 16 + l15;
    int r0c = (row0 < n) ? row0 : 0;
    int r1c = (row1 < n) ? row1 : 0;

    f32x4 acc[2][2];
#pragma unroll
    for (int tt = 0; tt < 2; tt++)
#pragma unroll
        for (int i = 0; i < 2; i++) acc[tt][i] = (f32x4){0.f, 0.f, 0.f, 0.f};

#pragma unroll
    for (int ks = 0; ks < 4; ks++) {
        f16x8 a0 = *(const f16x8*)(X + (size_t)r0c * 128 + kg * 8 + ks * 32);
        f16x8 a1 = *(const f16x8*)(X + (size_t)r1c * 128 + kg * 8 + ks * 32);
#pragma unroll
        for (int ct = 0; ct < 2; ct++) {
            f16x8 b = *(const f16x8*)(Wp + (size_t)((ct * 4 + ks) * 64 + lane) * 8);
            acc[0][ct] = __builtin_amdgcn_mfma_f32_16x16x32_f16(a0, b, acc[0][ct], 0, 0, 0);
            acc[1][ct] = __builtin_amdgcn_mfma_f32_16x16x32_f16(a1, b, acc[1][ct], 0, 0, 0);
        }
    }

#pragma unroll
    for (int tt = 0; tt < 2; tt++)
#pragma unroll
        for (int ct = 0; ct < 2; ct++)
#pragma unroll
            for (int r = 0; r < 4; r++)
                hs[wave][tt * 16 + kg * 4 + r][ct * 16 + l15] = __float2half(acc[tt][ct][r]);
    __syncthreads();

    // coalesced H store: 2 iters x (16 rows x 64 B contiguous), 16 B/lane
#pragma unroll
    for (int it = 0; it < 2; it++) {
        int lr    = it * 16 + (lane >> 2);     // 0..31
        int chunk = lane & 3;                  // 16B chunk within 64B row
        int orow  = wbase + lr;
        if (orow < n) {
            uint4 v = *(const uint4*)&hs[wave][lr][chunk * 8];
            *(uint4*)(H + (size_t)orow * 32 + chunk * 8) = v;
        }
    }

    // coef (1 head): lanes 0..31, row = lane
    if (lane < 32) {
        int orow = wbase + lane;
        if (orow < n) {
            const __half2* hp = (const __half2*)&hs[wave][lane][0];
            float s = 0.f, d = 0.f;
#pragma unroll
            for (int c2 = 0; c2 < 16; c2++) {
                float2 v = __half22float2(hp[c2]);
                s += v.x * a_s[2 * c2] + v.y * a_s[2 * c2 + 1];
                d += v.x * a_d[2 * c2] + v.y * a_d[2 * c2 + 1];
            }
            as_out[orow] = s;
            ad_out[orow] = d;
        }
    }
}

// ---------------- fused online-softmax aggregation, fp16 gathers -----------

__global__ __launch_bounds__(256)
void gat_fused_f16_kernel(const __half* __restrict__ Hm,
                          const float* __restrict__ as_,
                          const float* __restrict__ ad_,
                          const int* __restrict__ rowptr,
                          const int* __restrict__ csr,
                          const float* __restrict__ bias,
                          __half* __restrict__ out, int n) {
    constexpr int GS = 32;
    int t = threadIdx.x;
    int node = blockIdx.x * 8 + (t >> 5);
    if (node >= n) return;
    int tl = t & 31;
    int h  = tl >> 3;
    int k8 = tl & 7;
    const uint2* H8 = (const uint2*)Hm;     // 8 B = 4 halves per lane
    int e0 = rowptr[node], e1 = rowptr[node + 1];
    float ad_d = ad_[(size_t)node * 4 + h];

    int  ce  = e0 + k8;
    bool vA  = ce < e1;
    int  idxA = vA ? csr[ce] : 0;
    float asA = vA ? as_[(size_t)idxA * 4 + h] : 0.f;

    float m = -INFINITY, l = 0.f;
    float4 acc = make_float4(0.f, 0.f, 0.f, 0.f);

    for (int eb = e0; eb < e1; eb += 8) {
        uint2 u[8];
#pragma unroll
        for (int j = 0; j < 8; j++) {
            int src = __shfl(idxA, j, 8);
            u[j] = H8[(size_t)src * GS + tl];
        }

        int  ne  = eb + 8 + k8;
        bool vB  = ne < e1;
        int  idxB = vB ? csr[ne] : 0;
        float asB = vB ? as_[(size_t)idxB * 4 + h] : 0.f;

        float el = asA + ad_d;
        el = (el > 0.f) ? el : NEG_SLOPE * el;
        el = vA ? el : -INFINITY;

        float cm = el;
        cm = fmaxf(cm, __shfl_xor(cm, 1, 8));
        cm = fmaxf(cm, __shfl_xor(cm, 2, 8));
        cm = fmaxf(cm, __shfl_xor(cm, 4, 8));
        float m_new = fmaxf(m, cm);
        float scale = __expf(m - m_new);
        float p = vA ? __expf(el - m_new) : 0.f;

        float ps = p;
        ps += __shfl_xor(ps, 1, 8);
        ps += __shfl_xor(ps, 2, 8);
        ps += __shfl_xor(ps, 4, 8);
        l = l * scale + ps;
        acc.x *= scale; acc.y *= scale; acc.z *= scale; acc.w *= scale;
        m = m_new;

#pragma unroll
        for (int j = 0; j < 8; j++) {
            float pj  = __shfl(p, j, 8);
            float2 f01 = __half22float2(*(const __half2*)&u[j].x);
            float2 f23 = __half22float2(*(const __half2*)&u[j].y);
            acc.x += pj * f01.x; acc.y += pj * f01.y;
            acc.z += pj * f23.x; acc.w += pj * f23.y;
        }
        idxA = idxB; asA = asB; vA = vB;
    }

    float li = 1.f / (l + 1e-16f);
    float4 b4 = ((const float4*)bias)[tl];
    float4 o;
    o.x = fmaxf(acc.x * li + b4.x, 0.f);
    o.y = fmaxf(acc.y * li + b4.y, 0.f);
    o.z = fmaxf(acc.z * li + b4.z, 0.f);
    o.w = fmaxf(acc.w * li + b4.w, 0.f);
    h4pack po;
    po.a = __floats2half2_rn(o.x, o.y);
    po.b = __floats2half2_rn(o.z, o.w);
    ((h4pack*)out)[(size_t)node * 32 + tl] = po;
}

// ---------------- layer-2 fused: fp16 gathers + bias/relu + final linear ---

__global__ __launch_bounds__(256)
void gat_fused_l2_kernel(const __half* __restrict__ Hm,
                         const float* __restrict__ as_,
                         const float* __restrict__ ad_,
                         const int* __restrict__ rowptr,
                         const int* __restrict__ csr,
                         const float* __restrict__ bias,
                         const float* __restrict__ lw,
                         const float* __restrict__ lb,
                         float* __restrict__ out, int n) {
    int t = threadIdx.x;
    int node = blockIdx.x * 32 + (t >> 3);
    if (node >= n) return;
    int tl = t & 7;
    const uint2* H8 = (const uint2*)Hm;     // row = 8 uint2 (32 halves)
    int e0 = rowptr[node], e1 = rowptr[node + 1];
    float ad_d = ad_[node];

    int  ce  = e0 + tl;
    bool vA  = ce < e1;
    int  idxA = vA ? csr[ce] : 0;
    float asA = vA ? as_[idxA] : 0.f;

    float m = -INFINITY, l = 0.f;
    float4 acc = make_float4(0.f, 0.f, 0.f, 0.f);

    for (int eb = e0; eb < e1; eb += 8) {
        uint2 u[8];
#pragma unroll
        for (int j = 0; j < 8; j++) {
            int src = __shfl(idxA, j, 8);
            u[j] = H8[(size_t)src * 8 + tl];
        }

        int  ne  = eb + 8 + tl;
        bool vB  = ne < e1;
        int  idxB = vB ? csr[ne] : 0;
        float asB = vB ? as_[idxB] : 0.f;

        float el = asA + ad_d;
        el = (el > 0.f) ? el : NEG_SLOPE * el;
        el = vA ? el : -INFINITY;

        float cm = el;
        cm = fmaxf(cm, __shfl_xor(cm, 1, 8));
        cm = fmaxf(cm, __shfl_xor(cm, 2, 8));
        cm = fmaxf(cm, __shfl_xor(cm, 4, 8));
        float m_new = fmaxf(m, cm);
        float scale = __expf(m - m_new);
        float p = vA ? __expf(el - m_new) : 0.f;

        float ps = p;
        ps += __shfl_xor(ps, 1, 8);
        ps += __shfl_xor(ps, 2, 8);
        ps += __shfl_xor(ps, 4, 8);
        l = l * scale + ps;
        acc.x *= scale; acc.y *= scale; acc.z *= scale; acc.w *= scale;
        m = m_new;

#pragma unroll
        for (int j = 0; j < 8; j++) {
            float pj  = __shfl(p, j, 8);
            float2 f01 = __half22float2(*(const __half2*)&u[j].x);
            float2 f23 = __half22float2(*(const __half2*)&u[j].y);
            acc.x += pj * f01.x; acc.y += pj * f01.y;
            acc.z += pj * f23.x; acc.w += pj * f23.y;
        }
        idxA = idxB; asA = asB; vA = vB;
    }

    float li = 1.f / (l + 1e-16f);
    float4 b4 = ((const float4*)bias)[tl];
    float4 o;
    o.x = fmaxf(acc.x * li + b4.x, 0.f);
    o.y = fmaxf(acc.y * li + b4.y, 0.f);
    o.z = fmaxf(acc.z * li + b4.z, 0.f);
    o.w = fmaxf(acc.w * li + b4.w, 0.f);

    // fused final linear: lane tl computes classes tl + 8c (c = 0..4)
    float fin0 = lb[tl];
    float fin1 = lb[tl + 8];
    float fin2 = lb[tl + 16];
    float fin3 = lb[tl + 24];
    float fin4 = lb[tl + 32];
#pragma unroll
    for (int j = 0; j < 8; j++) {
        float vx = __shfl(o.x, j, 8);
        float vy = __shfl(o.y, j, 8);
        float vz = __shfl(o.z, j, 8);
        float vw = __shfl(o.w, j, 8);
        const float* l0 = lw + (size_t)(4 * j) * 40;   // rows 4j..4j+3 of lw[32,40]
#pragma unroll
        for (int c = 0; c < 5; c++) {
            int cls = tl + 8 * c;
            float v = vx * l0[cls] + vy * l0[40 + cls] + vz * l0[80 + cls] + vw * l0[120 + cls];
            if (c == 0) fin0 += v;
            else if (c == 1) fin1 += v;
            else if (c == 2) fin2 += v;
            else if (c == 3) fin3 += v;
            else fin4 += v;
        }
    }
    float* op = out + (size_t)node * 40;
    op[tl]      = fin0;
    op[tl + 8]  = fin1;
    op[tl + 16] = fin2;
    op[tl + 24] = fin3;
    op[tl + 32] = fin4;
}

// ---------------- launch ----------------

extern "C" void kernel_launch(void* const* d_in, const int* in_sizes, int n_in,
                              void* d_out, int out_size, void* d_ws, size_t ws_size,
                              hipStream_t stream) {
    const float* x   = (const float*)d_in[0];
    const int*   ei  = (const int*)d_in[1];
    const float* W0  = (const float*)d_in[2];
    const float* as0 = (const float*)d_in[3];
    const float* ad0 = (const float*)d_in[4];
    const float* b0  = (const float*)d_in[5];
    const float* W1  = (const float*)d_in[6];
    const float* as1 = (const float*)d_in[7];
    const float* ad1 = (const float*)d_in[8];
    const float* b1  = (const float*)d_in[9];
    const float* W2  = (const float*)d_in[10];
    const float* as2 = (const float*)d_in[11];
    const float* ad2 = (const float*)d_in[12];
    const float* b2  = (const float*)d_in[13];
    const float* lw  = (const float*)d_in[14];
    const float* lb  = (const float*)d_in[15];
    float* out = (float*)d_out;

    const int n    = in_sizes[0] / 128;   // 100000 (= 32 * 3125)
    const int eraw = in_sizes[1] / 2;     // 1600000
    const int etot = eraw + n;
    const int nb   = (n + 1023) / 1024;

    char* wsp = (char*)d_ws;
    size_t off = 0;
    auto alloc = [&](size_t bytes) -> void* {
        void* p = wsp + off;
        off += (bytes + 255) & ~(size_t)255;
        return p;
    };
    __half* h16    = (__half*)alloc((size_t)n * 128 * 2);  // per-layer h table
    __half* buf16  = (__half*)alloc((size_t)n * 128 * 2);  // inter-layer activations
    __half* h2     = (__half*)alloc((size_t)n * 32 * 2);   // layer-2 h table
    __half* Wp0    = (__half*)alloc((size_t)128 * 128 * 2);
    __half* Wp1    = (__half*)alloc((size_t)128 * 128 * 2);
    __half* Wp2    = (__half*)alloc((size_t)128 * 32 * 2);
    float*  asb    = (float*)alloc((size_t)n * 4 * 4);
    float*  adb    = (float*)alloc((size_t)n * 4 * 4);
    float*  asb2   = (float*)alloc((size_t)n * 4);
    float*  adb2   = (float*)alloc((size_t)n * 4);
    int*    deg    = (int*)alloc((size_t)n * 4);
    int*    rank   = (int*)alloc((size_t)etot * 4);
    int*    rowptr = (int*)alloc((size_t)(n + 1) * 4);
    int*    csr    = (int*)alloc((size_t)etot * 4);
    int*    bsum   = (int*)alloc((size_t)nb * 4);
    int*    boffs  = (int*)alloc((size_t)nb * 4);

    // --- CSR build (two-phase, rank precomputed) + weight prep ---
    hipMemsetAsync(deg, 0, (size_t)n * 4, stream);
    count_rank_kernel<<<(etot + 255) / 256, 256, 0, stream>>>(ei, eraw, n, deg, rank);
    wpack_all_kernel<<<144, 256, 0, stream>>>(W0, W1, W2, Wp0, Wp1, Wp2);
    scan_local_kernel<<<nb, 1024, 0, stream>>>(deg, rowptr, bsum, n);
    scan_sums_kernel<<<1, 128, 0, stream>>>(bsum, boffs, nb);
    scan_add_kernel<<<(n + 255) / 256, 256, 0, stream>>>(rowptr, boffs, n, etot);
    scatter2_kernel<<<(etot + 255) / 256, 256, 0, stream>>>(ei, rank, eraw, n, rowptr, csr);

    const int gblocks = (n + 127) / 128;

    // --- layer 0: 128 -> 4x32, concat ---
    gemm_mfma_coef_kernel<true><<<gblocks, 256, 0, stream>>>(x, Wp0, as0, ad0, h16, asb, adb, n);
    gat_fused_f16_kernel<<<(n + 7) / 8, 256, 0, stream>>>(h16, asb, adb, rowptr, csr, b0, buf16, n);

    // --- layer 1: 128 -> 4x32, concat ---
    gemm_mfma_coef_kernel<false><<<gblocks, 256, 0, stream>>>(buf16, Wp1, as1, ad1, h16, asb, adb, n);
    gat_fused_f16_kernel<<<(n + 7) / 8, 256, 0, stream>>>(h16, asb, adb, rowptr, csr, b1, buf16, n);

    // --- layer 2: 128 -> 1x32 (MFMA + fused coef), + fused final linear ---
    gemm_mfma_l2_kernel<<<gblocks, 256, 0, stream>>>(buf16, Wp2, as2, ad2, h2, asb2, adb2, n);
    gat_fused_l2_kernel<<<(n + 31) / 32, 256, 0, stream>>>(h2, asb2, adb2, rowptr, csr, b2, lw, lb, out, n);
}